// Round 16
// baseline (81.256 us; speedup 1.0000x reference)
//
#include <hip/hip_runtime.h>

#define NQ 12
#define NL 4
#define NGATES (NQ * NL)
#define INV_2PI 0.15915494309189535f

// ---------------------------------------------------------------------------
// Diagonalized formulation (round-12 algebra, 16 amps/thread, FUSED state).
// Every compiled gate is exp(-i th/2 X_m) -> all 48 commute; conjugating by
// H^x12 diagonalizes the circuit: U = H D H, D|q> = e^{-iPhi(q)}|q>,
//   Phi(q) = sum_g (th_g/2)(-1)^{parity(q & m_g)}  (layer-1 included).
// <Z_w> = sum_q conj(psi(q^rho_w)) psi(q), rho_w = row of L^-1 (HZH = X);
// psi = A e^{-iPhi}, A real product state (a0 = cy+sy, a1 = cy-sy, scale 2^-6).
// Layout (A = I): p[3:0] = reg (qubits 11..8), p[9:4] = lane bits 0..5
// (qubits 7..2), p[10] = tid6 (qubit 1), p[11] = tid7 (qubit 0).
// FUSED STATE (the round-16 change): one v2f st[16] holds A in .x (phase 1),
// Phi in .y (phase 2), and is converted IN PLACE to psi = (A cos, -A sin)
// (phase 3). Peak live regs ~45 (was ~80 with separate A/W/st arrays ->
// r14's 280 MB scratch at wpe(4)). Now wpe(4) fits: 4 waves/SIMD (the max
// the 33 KB LDS allows: 4 blocks/CU) with zero spill, vs r15's 3.
// Correlations: cheap lane masks via DPP/permlane; others via ONE full LDS
// stash of st (32 KB, one barrier), each lag computed and retired in turn.
// ---------------------------------------------------------------------------
struct Masks { unsigned rx[NGATES]; unsigned z[NQ]; };

constexpr Masks compute_masks() {
  Masks mk{};
  unsigned col[NQ] = {};
  for (int b = 0; b < NQ; ++b) col[b] = 1u << b;
  int g = 0;
  for (int l = 0; l < NL; ++l) {
    for (int w = 0; w < NQ; ++w) mk.rx[g++] = col[NQ - 1 - w];
    for (int i = 0; i < NQ; ++i) {           // ring CNOT(i, (i+1)%12)
      int cb = NQ - 1 - i;
      int tb = NQ - 1 - ((i + 1) % NQ);
      col[cb] ^= col[tb];
    }
  }
  unsigned A[NQ] = {}, Inv[NQ] = {};
  for (int i = 0; i < NQ; ++i) {
    unsigned rowv = 0;
    for (int j = 0; j < NQ; ++j) rowv |= ((col[j] >> i) & 1u) << j;
    A[i] = rowv;
    Inv[i] = 1u << i;
  }
  for (int c = 0; c < NQ; ++c) {
    int piv = c;
    while (((A[piv] >> c) & 1u) == 0u) ++piv;
    unsigned ta = A[piv]; A[piv] = A[c]; A[c] = ta;
    unsigned ti = Inv[piv]; Inv[piv] = Inv[c]; Inv[c] = ti;
    for (int r = 0; r < NQ; ++r)
      if (r != c && ((A[r] >> c) & 1u)) { A[r] ^= A[c]; Inv[r] ^= Inv[c]; }
  }
  for (int w = 0; w < NQ; ++w) mk.z[w] = Inv[NQ - 1 - w];
  return mk;
}

constexpr Masks MK = compute_masks();

typedef float v2f __attribute__((ext_vector_type(2)));
typedef int   v2i __attribute__((ext_vector_type(2)));

template <int CTRL>
__device__ __forceinline__ int dpp_i(int x) {
  return __builtin_amdgcn_update_dpp(x, x, CTRL, 0xf, 0xf, false);
}

// VALU cost of a cross-lane xor-mask fetch (DPP/permlane path).
constexpr int dppcost(int ml) {
  int m4 = ml & 15;
  int c = (m4 == 0) ? 0
        : ((m4 == 1 || m4 == 2 || m4 == 3 || m4 == 7 || m4 == 8 || m4 == 15) ? 1 : 2);
  if (ml & 16) c += 2;
  if (ml & 32) c += 2;
  return c;
}

// v[lane ^ ML] on the VALU pipe. quad_perm xor1=0xB1 xor2=0x4E xor3=0x1B;
// row_half_mirror(xor7)=0x141; row_ror:8(xor8)=0x128; row_mirror(xor15)=0x140.
template <int ML>
__device__ __forceinline__ float fetchx(float v) {
  static_assert(ML >= 1 && ML < 64, "lane mask");
  int x = __float_as_int(v);
  constexpr int m4 = ML & 15;
  if constexpr (m4 == 1)       x = dpp_i<0xB1>(x);
  else if constexpr (m4 == 2)  x = dpp_i<0x4E>(x);
  else if constexpr (m4 == 3)  x = dpp_i<0x1B>(x);
  else if constexpr (m4 == 4)  { x = dpp_i<0x141>(x); x = dpp_i<0x1B>(x); }
  else if constexpr (m4 == 5)  { x = dpp_i<0x141>(x); x = dpp_i<0x4E>(x); }
  else if constexpr (m4 == 6)  { x = dpp_i<0x141>(x); x = dpp_i<0xB1>(x); }
  else if constexpr (m4 == 7)  x = dpp_i<0x141>(x);
  else if constexpr (m4 == 8)  x = dpp_i<0x128>(x);
  else if constexpr (m4 == 9)  { x = dpp_i<0x128>(x); x = dpp_i<0xB1>(x); }
  else if constexpr (m4 == 10) { x = dpp_i<0x128>(x); x = dpp_i<0x4E>(x); }
  else if constexpr (m4 == 11) { x = dpp_i<0x128>(x); x = dpp_i<0x1B>(x); }
  else if constexpr (m4 == 12) { x = dpp_i<0x140>(x); x = dpp_i<0x1B>(x); }
  else if constexpr (m4 == 13) { x = dpp_i<0x140>(x); x = dpp_i<0x4E>(x); }
  else if constexpr (m4 == 14) { x = dpp_i<0x140>(x); x = dpp_i<0xB1>(x); }
  else if constexpr (m4 == 15) x = dpp_i<0x140>(x);
  if constexpr (ML & 16) {
    v2i r = __builtin_amdgcn_permlane16_swap(x, x, false, false);
    x = (threadIdx.x & 16) ? r.x : r.y;
  }
  if constexpr (ML & 32) {
    v2i r = __builtin_amdgcn_permlane32_swap(x, x, false, false);
    x = (threadIdx.x & 32) ? r.x : r.y;
  }
  return __int_as_float(x);
}

// 64-lane sum of acc.x + acc.y.
__device__ __forceinline__ float redl(v2f acc) {
  float s = acc.x + acc.y;
  {
    v2i r = __builtin_amdgcn_permlane32_swap(__float_as_int(s),
                                             __float_as_int(s), false, false);
    s = __int_as_float(r.x) + __int_as_float(r.y);
  }
  {
    v2i r = __builtin_amdgcn_permlane16_swap(__float_as_int(s),
                                             __float_as_int(s), false, false);
    s = __int_as_float(r.x) + __int_as_float(r.y);
  }
  s += fetchx<8>(s);
  s += fetchx<4>(s);
  s += fetchx<2>(s);
  s += fetchx<1>(s);
  return s;
}

// Accumulate +-phi_g into st[m & 15].y; sign = parity(tid & ((m>>4) & 0xFF)).
template <int G>
__device__ __forceinline__ void accum_signs(v2f (&st)[16],
                                            const float* __restrict__ phi,
                                            int tid) {
  if constexpr (G < NGATES) {
    constexpr unsigned m = MK.rx[G];
    constexpr int mlo = (int)(m & 15u);
    constexpr int tmask = (int)((m >> 4) & 0xFFu);
    const float th = phi[G];                 // uniform -> s_load, SGPR
    if constexpr (tmask == 0) {
      st[mlo].y += th;
    } else {
      const int sgn = (__popc(tid & tmask) & 1) << 31;
      st[mlo].y += __int_as_float(__float_as_int(th) ^ sgn);
    }
    accum_signs<G + 1>(st, phi, tid);
  }
}

// Is correlation lag w handled via the LDS stash?
constexpr bool is_lds(int w) {
  unsigned zm = MK.z[w];
  int tz = (int)((zm >> 4) & 0xFFu);
  return (tz >> 6) != 0 || dppcost(tz & 63) > 2;
}

// Cheap lags: partner via DPP/permlane (lane bits only), 16-amp dot, reduce.
template <int W_>
__device__ __forceinline__ void corr_dpp(const v2f (&st)[16], float* zb,
                                         int lane, int wv) {
  if constexpr (W_ < NQ) {
    if constexpr (!is_lds(W_)) {
      constexpr unsigned zm = MK.z[W_];
      constexpr int mr = (int)(zm & 15u);
      constexpr int ml = (int)((zm >> 4) & 63u);
      v2f acc; acc.x = 0.f; acc.y = 0.f;
#pragma unroll
      for (int r = 0; r < 16; ++r) {
        v2f t;
        if constexpr (ml == 0) t = st[r ^ mr];
        else { t.x = fetchx<ml>(st[r ^ mr].x); t.y = fetchx<ml>(st[r ^ mr].y); }
        acc += st[r] * t;                    // v_pk_fma_f32
      }
      float s = redl(acc);
      if (lane == 0) zb[wv * NQ + W_] = s;
    }
    corr_dpp<W_ + 1>(st, zb, lane, wv);
  }
}

// LDS-stash lags: full st stashed once (slot k, thread t at xbuf[k*256+t]).
// Partner thread = tid ^ ((zm>>4) & 0xFF); slot k serves local reg k^mr.
template <int W_>
__device__ __forceinline__ void corr_lds(const v2f (&st)[16],
                                         const v2f* xbuf, float* zb,
                                         int tid, int lane, int wv) {
  if constexpr (W_ < NQ) {
    if constexpr (is_lds(W_)) {
      constexpr unsigned zm = MK.z[W_];
      constexpr int mr = (int)(zm & 15u);
      constexpr int tz = (int)((zm >> 4) & 0xFFu);
      const int ptid = tid ^ tz;
      v2f acc; acc.x = 0.f; acc.y = 0.f;
#pragma unroll
      for (int k = 0; k < 16; ++k)
        acc += st[k] * xbuf[(k ^ mr) * 256 + ptid];
      float s = redl(acc);
      if (lane == 0) zb[wv * NQ + W_] = s;
    }
    corr_lds<W_ + 1>(st, xbuf, zb, tid, lane, wv);
  }
}

// Prep: 48 batch-uniform gate angles -> th_g/(4pi) (revolutions of th/2).
__global__ void prep_kernel(const float* __restrict__ wts,
                            float* __restrict__ phi) {
  const int i = threadIdx.x;
  if (i < NGATES) phi[i] = wts[i] * (0.5f * INV_2PI);
}

__global__ __attribute__((amdgpu_flat_work_group_size(256, 256),
                          amdgpu_waves_per_eu(4)))
void qsim_kernel(const float* __restrict__ x,
                 const float* __restrict__ phi,
                 float* __restrict__ out) {
  __shared__ v2f xbuf[16 * 256];       // 32 KiB full-state stash
  __shared__ float zb[4 * NQ];

  const int bidx = blockIdx.x;         // one batch element per 256-thr block
  const int tid  = threadIdx.x;
  const int lane = tid & 63;
  const int wv   = tid >> 6;

  const float4* xv = reinterpret_cast<const float4*>(x + bidx * NQ);
  float4 q0 = xv[0], q1 = xv[1], q2 = xv[2];
  const float xa[NQ] = {q0.x, q0.y, q0.z, q0.w, q1.x, q1.y, q1.z, q1.w,
                        q2.x, q2.y, q2.z, q2.w};

  v2f st[16];
#pragma unroll
  for (int k = 0; k < 16; ++k) { st[k].y = 0.f; }   // Phi accumulator

  // ---- Phase 1: real product amplitude A -> st[].x (a0 = cy+sy, a1 = cy-sy).
  // Scalar: qubit 0 = tid7, qubit 1 = tid6, qubits 2..7 = tid bits 5..0.
  {
    float rv = xa[0] * (0.5f * INV_2PI);
    float sy = __builtin_amdgcn_sinf(rv), cy = __builtin_amdgcn_cosf(rv);
    float F = 0.015625f * (((tid >> 7) & 1) ? (cy - sy) : (cy + sy));  // 2^-6
    rv = xa[1] * (0.5f * INV_2PI);
    sy = __builtin_amdgcn_sinf(rv); cy = __builtin_amdgcn_cosf(rv);
    F *= ((tid >> 6) & 1) ? (cy - sy) : (cy + sy);
#pragma unroll
    for (int w = 2; w <= 7; ++w) {
      rv = xa[w] * (0.5f * INV_2PI);
      sy = __builtin_amdgcn_sinf(rv); cy = __builtin_amdgcn_cosf(rv);
      F *= ((tid >> (7 - w)) & 1) ? (cy - sy) : (cy + sy);
    }
    st[0].x = F;
#pragma unroll
    for (int j = 0; j < 4; ++j) {                // reg bit j = qubit 11-j
      const int wq = 11 - j;
      rv = xa[wq] * (0.5f * INV_2PI);
      sy = __builtin_amdgcn_sinf(rv); cy = __builtin_amdgcn_cosf(rv);
      const float g0 = cy + sy, g1 = cy - sy;
#pragma unroll
      for (int k = 0; k < 8; ++k) {
        if (k < (1 << j)) {
          float base = st[k].x;
          st[k | (1 << j)].x = base * g1;
          st[k].x            = base * g0;
        }
      }
    }
  }

  // ---- Phase 2: Phi into st[].y: signed accumulation + 4-bit WHT.
  accum_signs<0>(st, phi, tid);
#pragma unroll
  for (int j = 0; j < 4; ++j) {
#pragma unroll
    for (int k = 0; k < 16; ++k) {
      if (!(k & (1 << j))) {
        float a = st[k].y, b = st[k | (1 << j)].y;
        st[k].y            = a + b;
        st[k | (1 << j)].y = a - b;
      }
    }
  }

  // ---- Phase 3: in-place psi = A e^{-i Phi}: (a, w) -> (a cos w, -a sin w).
#pragma unroll
  for (int r = 0; r < 16; ++r) {
    float a = st[r].x, w = st[r].y;
    float s = __builtin_amdgcn_sinf(w);
    float c = __builtin_amdgcn_cosf(w);
    st[r].x = a * c;
    st[r].y = -a * s;
  }

  // ---- Phase 4: <Z_w> = sum_q Re[psi*(q^rho_w) psi(q)].
  corr_dpp<0>(st, zb, lane, wv);

#pragma unroll
  for (int k = 0; k < 16; ++k) xbuf[k * 256 + tid] = st[k];
  __syncthreads();
  corr_lds<0>(st, xbuf, zb, tid, lane, wv);

  __syncthreads();
  if (tid < NQ)
    out[bidx * NQ + tid] =
        zb[tid] + zb[NQ + tid] + zb[2 * NQ + tid] + zb[3 * NQ + tid];
}

extern "C" void kernel_launch(void* const* d_in, const int* in_sizes, int n_in,
                              void* d_out, int out_size, void* d_ws, size_t ws_size,
                              hipStream_t stream) {
  const float* x   = (const float*)d_in[0];   // (4096, 12) f32
  const float* wts = (const float*)d_in[1];   // (4, 12) f32
  float* out = (float*)d_out;                 // (4096, 12) f32
  float* phi = (float*)d_ws;                  // 48 floats: th/(4pi)

  prep_kernel<<<1, 64, 0, stream>>>(wts, phi);

  const int batch = in_sizes[0] / NQ;         // 4096
  dim3 grid(batch);
  dim3 block(256);
  qsim_kernel<<<grid, block, 0, stream>>>(x, phi, out);
}

// Round 17
// 32.643 us; speedup vs baseline: 2.4892x; 2.4892x over previous
//
#include <hip/hip_runtime.h>

#define NQ 12
#define NL 4
#define NGATES (NQ * NL)
#define INV_2PI 0.15915494309189535f

// ---------------------------------------------------------------------------
// Diagonalized formulation (round-15 config, prep inlined).
// Every compiled gate is exp(-i th/2 X_m) -> all 48 commute; conjugating by
// H^x12 diagonalizes the circuit: U = H D H, D|q> = e^{-iPhi(q)}|q>,
//   Phi(q) = sum_g (th_g/2)(-1)^{parity(q & m_g)}  (layer-1 included).
// <Z_w> = sum_q conj(psi(q^rho_w)) psi(q), rho_w = row of L^-1 (HZH = X);
// psi = A e^{-iPhi}, A real product state (a0 = cy+sy, a1 = cy-sy, scale 2^-6).
// Layout (A = I): p[3:0] = reg (qubits 11..8), p[9:4] = lane bits 0..5
// (qubits 7..2), p[10] = tid6 (qubit 1), p[11] = tid7 (qubit 0).
// 256 thr/elem, 16 amps/thread.
// waves_per_eu(3): wpe(4)'s 128-budget splits 64 arch + 64 acc and SPILLS
// ~45 floats/thread (r14 & r16: identical 280 MB scratch traffic; r16 proved
// source-level array fusion is an SSA no-op - liveness is structural).
// wpe(3) grants arch ~76+; r15 ran clean (WRITE=output only) at 38 us.
// PREP INLINED (r17): accumulation is LINEAR in the angles -> accumulate raw
// +-wts[g] (uniform s_loads) and scale the 16 W values once by 0.5*INV_2PI
// (16 v_mul vs 48), killing the separate prep launch + its graph dependency.
// Phase 4 reordered: LDS stash writes issued BEFORE the 7 DPP lags so DS
// write latency hides under VALU, shortening the barrier wait.
// Correlations: cheap lane masks via DPP/permlane; wave-crossing/expensive
// masks via ONE full LDS stash of st (32 KB, one barrier).
// ---------------------------------------------------------------------------
struct Masks { unsigned rx[NGATES]; unsigned z[NQ]; };

constexpr Masks compute_masks() {
  Masks mk{};
  unsigned col[NQ] = {};
  for (int b = 0; b < NQ; ++b) col[b] = 1u << b;
  int g = 0;
  for (int l = 0; l < NL; ++l) {
    for (int w = 0; w < NQ; ++w) mk.rx[g++] = col[NQ - 1 - w];
    for (int i = 0; i < NQ; ++i) {           // ring CNOT(i, (i+1)%12)
      int cb = NQ - 1 - i;
      int tb = NQ - 1 - ((i + 1) % NQ);
      col[cb] ^= col[tb];
    }
  }
  unsigned A[NQ] = {}, Inv[NQ] = {};
  for (int i = 0; i < NQ; ++i) {
    unsigned rowv = 0;
    for (int j = 0; j < NQ; ++j) rowv |= ((col[j] >> i) & 1u) << j;
    A[i] = rowv;
    Inv[i] = 1u << i;
  }
  for (int c = 0; c < NQ; ++c) {
    int piv = c;
    while (((A[piv] >> c) & 1u) == 0u) ++piv;
    unsigned ta = A[piv]; A[piv] = A[c]; A[c] = ta;
    unsigned ti = Inv[piv]; Inv[piv] = Inv[c]; Inv[c] = ti;
    for (int r = 0; r < NQ; ++r)
      if (r != c && ((A[r] >> c) & 1u)) { A[r] ^= A[c]; Inv[r] ^= Inv[c]; }
  }
  for (int w = 0; w < NQ; ++w) mk.z[w] = Inv[NQ - 1 - w];
  return mk;
}

constexpr Masks MK = compute_masks();

typedef float v2f __attribute__((ext_vector_type(2)));
typedef int   v2i __attribute__((ext_vector_type(2)));

template <int CTRL>
__device__ __forceinline__ int dpp_i(int x) {
  return __builtin_amdgcn_update_dpp(x, x, CTRL, 0xf, 0xf, false);
}

// VALU cost of a cross-lane xor-mask fetch (DPP/permlane path).
constexpr int dppcost(int ml) {
  int m4 = ml & 15;
  int c = (m4 == 0) ? 0
        : ((m4 == 1 || m4 == 2 || m4 == 3 || m4 == 7 || m4 == 8 || m4 == 15) ? 1 : 2);
  if (ml & 16) c += 2;
  if (ml & 32) c += 2;
  return c;
}

// v[lane ^ ML] on the VALU pipe. quad_perm xor1=0xB1 xor2=0x4E xor3=0x1B;
// row_half_mirror(xor7)=0x141; row_ror:8(xor8)=0x128; row_mirror(xor15)=0x140.
template <int ML>
__device__ __forceinline__ float fetchx(float v) {
  static_assert(ML >= 1 && ML < 64, "lane mask");
  int x = __float_as_int(v);
  constexpr int m4 = ML & 15;
  if constexpr (m4 == 1)       x = dpp_i<0xB1>(x);
  else if constexpr (m4 == 2)  x = dpp_i<0x4E>(x);
  else if constexpr (m4 == 3)  x = dpp_i<0x1B>(x);
  else if constexpr (m4 == 4)  { x = dpp_i<0x141>(x); x = dpp_i<0x1B>(x); }
  else if constexpr (m4 == 5)  { x = dpp_i<0x141>(x); x = dpp_i<0x4E>(x); }
  else if constexpr (m4 == 6)  { x = dpp_i<0x141>(x); x = dpp_i<0xB1>(x); }
  else if constexpr (m4 == 7)  x = dpp_i<0x141>(x);
  else if constexpr (m4 == 8)  x = dpp_i<0x128>(x);
  else if constexpr (m4 == 9)  { x = dpp_i<0x128>(x); x = dpp_i<0xB1>(x); }
  else if constexpr (m4 == 10) { x = dpp_i<0x128>(x); x = dpp_i<0x4E>(x); }
  else if constexpr (m4 == 11) { x = dpp_i<0x128>(x); x = dpp_i<0x1B>(x); }
  else if constexpr (m4 == 12) { x = dpp_i<0x140>(x); x = dpp_i<0x1B>(x); }
  else if constexpr (m4 == 13) { x = dpp_i<0x140>(x); x = dpp_i<0x4E>(x); }
  else if constexpr (m4 == 14) { x = dpp_i<0x140>(x); x = dpp_i<0xB1>(x); }
  else if constexpr (m4 == 15) x = dpp_i<0x140>(x);
  if constexpr (ML & 16) {
    v2i r = __builtin_amdgcn_permlane16_swap(x, x, false, false);
    x = (threadIdx.x & 16) ? r.x : r.y;
  }
  if constexpr (ML & 32) {
    v2i r = __builtin_amdgcn_permlane32_swap(x, x, false, false);
    x = (threadIdx.x & 32) ? r.x : r.y;
  }
  return __int_as_float(x);
}

// 64-lane sum of acc.x + acc.y.
__device__ __forceinline__ float redl(v2f acc) {
  float s = acc.x + acc.y;
  {
    v2i r = __builtin_amdgcn_permlane32_swap(__float_as_int(s),
                                             __float_as_int(s), false, false);
    s = __int_as_float(r.x) + __int_as_float(r.y);
  }
  {
    v2i r = __builtin_amdgcn_permlane16_swap(__float_as_int(s),
                                             __float_as_int(s), false, false);
    s = __int_as_float(r.x) + __int_as_float(r.y);
  }
  s += fetchx<8>(s);
  s += fetchx<4>(s);
  s += fetchx<2>(s);
  s += fetchx<1>(s);
  return s;
}

// Accumulate +-wts[g] (RAW angle; scale applied once after) into W[m & 15];
// sign = parity(tid & ((m>>4) & 0xFF)).
template <int G>
__device__ __forceinline__ void accum_signs(float (&W)[16],
                                            const float* __restrict__ wts,
                                            int tid) {
  if constexpr (G < NGATES) {
    constexpr unsigned m = MK.rx[G];
    constexpr int mlo = (int)(m & 15u);
    constexpr int tmask = (int)((m >> 4) & 0xFFu);
    const float th = wts[G];                 // uniform -> s_load, SGPR
    if constexpr (tmask == 0) {
      W[mlo] += th;
    } else {
      const int sgn = (__popc(tid & tmask) & 1) << 31;
      W[mlo] += __int_as_float(__float_as_int(th) ^ sgn);
    }
    accum_signs<G + 1>(W, wts, tid);
  }
}

// Is correlation lag w handled via the LDS stash?
constexpr bool is_lds(int w) {
  unsigned zm = MK.z[w];
  int tz = (int)((zm >> 4) & 0xFFu);
  return (tz >> 6) != 0 || dppcost(tz & 63) > 2;
}

// Cheap lags: partner via DPP/permlane (lane bits only), 16-amp dot, reduce.
template <int W_>
__device__ __forceinline__ void corr_dpp(const v2f (&st)[16], float* zb,
                                         int lane, int wv) {
  if constexpr (W_ < NQ) {
    if constexpr (!is_lds(W_)) {
      constexpr unsigned zm = MK.z[W_];
      constexpr int mr = (int)(zm & 15u);
      constexpr int ml = (int)((zm >> 4) & 63u);
      v2f acc; acc.x = 0.f; acc.y = 0.f;
#pragma unroll
      for (int r = 0; r < 16; ++r) {
        v2f t;
        if constexpr (ml == 0) t = st[r ^ mr];
        else { t.x = fetchx<ml>(st[r ^ mr].x); t.y = fetchx<ml>(st[r ^ mr].y); }
        acc += st[r] * t;                    // v_pk_fma_f32
      }
      float s = redl(acc);
      if (lane == 0) zb[wv * NQ + W_] = s;
    }
    corr_dpp<W_ + 1>(st, zb, lane, wv);
  }
}

// LDS-stash lags: full st stashed once (slot k, thread t at xbuf[k*256+t]).
// Partner thread = tid ^ ((zm>>4) & 0xFF); slot k serves local reg k^mr.
template <int W_>
__device__ __forceinline__ void corr_lds(const v2f (&st)[16],
                                         const v2f* xbuf, float* zb,
                                         int tid, int lane, int wv) {
  if constexpr (W_ < NQ) {
    if constexpr (is_lds(W_)) {
      constexpr unsigned zm = MK.z[W_];
      constexpr int mr = (int)(zm & 15u);
      constexpr int tz = (int)((zm >> 4) & 0xFFu);
      const int ptid = tid ^ tz;
      v2f acc; acc.x = 0.f; acc.y = 0.f;
#pragma unroll
      for (int k = 0; k < 16; ++k)
        acc += st[k] * xbuf[(k ^ mr) * 256 + ptid];
      float s = redl(acc);
      if (lane == 0) zb[wv * NQ + W_] = s;
    }
    corr_lds<W_ + 1>(st, xbuf, zb, tid, lane, wv);
  }
}

__global__ __attribute__((amdgpu_flat_work_group_size(256, 256),
                          amdgpu_waves_per_eu(3)))
void qsim_kernel(const float* __restrict__ x,
                 const float* __restrict__ wts,
                 float* __restrict__ out) {
  __shared__ v2f xbuf[16 * 256];       // 32 KiB full-state stash
  __shared__ float zb[4 * NQ];

  const int bidx = blockIdx.x;         // one batch element per 256-thr block
  const int tid  = threadIdx.x;
  const int lane = tid & 63;
  const int wv   = tid >> 6;

  const float4* xv = reinterpret_cast<const float4*>(x + bidx * NQ);
  float4 q0 = xv[0], q1 = xv[1], q2 = xv[2];
  const float xa[NQ] = {q0.x, q0.y, q0.z, q0.w, q1.x, q1.y, q1.z, q1.w,
                        q2.x, q2.y, q2.z, q2.w};

  // ---- Phase 1: real product amplitude A (a0 = cy+sy, a1 = cy-sy).
  // Scalar: qubit 0 = tid7, qubit 1 = tid6, qubits 2..7 = tid bits 5..0.
  float A[16];
  {
    float rv = xa[0] * (0.5f * INV_2PI);
    float sy = __builtin_amdgcn_sinf(rv), cy = __builtin_amdgcn_cosf(rv);
    float F = 0.015625f * (((tid >> 7) & 1) ? (cy - sy) : (cy + sy));  // 2^-6
    rv = xa[1] * (0.5f * INV_2PI);
    sy = __builtin_amdgcn_sinf(rv); cy = __builtin_amdgcn_cosf(rv);
    F *= ((tid >> 6) & 1) ? (cy - sy) : (cy + sy);
#pragma unroll
    for (int w = 2; w <= 7; ++w) {
      rv = xa[w] * (0.5f * INV_2PI);
      sy = __builtin_amdgcn_sinf(rv); cy = __builtin_amdgcn_cosf(rv);
      F *= ((tid >> (7 - w)) & 1) ? (cy - sy) : (cy + sy);
    }
    A[0] = F;
#pragma unroll
    for (int j = 0; j < 4; ++j) {                // reg bit j = qubit 11-j
      const int wq = 11 - j;
      rv = xa[wq] * (0.5f * INV_2PI);
      sy = __builtin_amdgcn_sinf(rv); cy = __builtin_amdgcn_cosf(rv);
      const float g0 = cy + sy, g1 = cy - sy;
#pragma unroll
      for (int k = 0; k < 8; ++k) {
        if (k < (1 << j)) {
          float base = A[k];
          A[k | (1 << j)] = base * g1;
          A[k]            = base * g0;
        }
      }
    }
  }

  // ---- Phase 2: Phi = signed accumulation of raw wts, scale once, 4-bit WHT.
  float W[16];
#pragma unroll
  for (int k = 0; k < 16; ++k) W[k] = 0.f;
  accum_signs<0>(W, wts, tid);
#pragma unroll
  for (int k = 0; k < 16; ++k) W[k] *= (0.5f * INV_2PI);   // th/2 -> revolutions
#pragma unroll
  for (int j = 0; j < 4; ++j) {
#pragma unroll
    for (int k = 0; k < 16; ++k) {
      if (!(k & (1 << j))) {
        float a = W[k], b = W[k | (1 << j)];
        W[k]            = a + b;
        W[k | (1 << j)] = a - b;
      }
    }
  }

  // ---- Phase 3: psi = A e^{-i Phi}; A and W die into st (32 VGPRs).
  v2f st[16];
#pragma unroll
  for (int r = 0; r < 16; ++r) {
    float s = __builtin_amdgcn_sinf(W[r]);
    float c = __builtin_amdgcn_cosf(W[r]);
    st[r].x = A[r] * c;
    st[r].y = -A[r] * s;
  }

  // ---- Phase 4: <Z_w> = sum_q Re[psi*(q^rho_w) psi(q)].
  // Stash write FIRST so DS-write latency hides under the DPP-lag VALU work.
#pragma unroll
  for (int k = 0; k < 16; ++k) xbuf[k * 256 + tid] = st[k];

  corr_dpp<0>(st, zb, lane, wv);

  __syncthreads();
  corr_lds<0>(st, xbuf, zb, tid, lane, wv);

  __syncthreads();
  if (tid < NQ)
    out[bidx * NQ + tid] =
        zb[tid] + zb[NQ + tid] + zb[2 * NQ + tid] + zb[3 * NQ + tid];
}

extern "C" void kernel_launch(void* const* d_in, const int* in_sizes, int n_in,
                              void* d_out, int out_size, void* d_ws, size_t ws_size,
                              hipStream_t stream) {
  const float* x   = (const float*)d_in[0];   // (4096, 12) f32
  const float* wts = (const float*)d_in[1];   // (4, 12) f32
  float* out = (float*)d_out;                 // (4096, 12) f32

  const int batch = in_sizes[0] / NQ;         // 4096
  dim3 grid(batch);
  dim3 block(256);
  qsim_kernel<<<grid, block, 0, stream>>>(x, wts, out);
}